// Round 5
// baseline (346.009 us; speedup 1.0000x reference)
//
#include <hip/hip_runtime.h>
#include <hip/hip_bf16.h>
#include <math.h>

// Problem constants (structure is static per the reference):
//   B=32768 graphs, 8 nodes/graph, fully-connected no-self-loop => 56 edges/graph
//   K=4 Chebyshev, channels 8 -> 16 -> 32 -> 64, MLP 512->256->128->5, log_softmax
#define NGRAPH 32768

typedef __attribute__((ext_vector_type(8))) short short8;
typedef __attribute__((ext_vector_type(4))) float f32x4;

// ---------------------------------------------------------------- cheb stack
struct WaveScratch {
    float L[64];      // 8x8 scaled Laplacian, L[d*8+s]
    float dis[8];     // D^{-1/2}
    float bufX[256];  // current layer input (8 x C_in), also layer output
    float bufT1[256];
    float bufT2[256];
};

// acc += T (8 x CIN, LDS, node-major) @ Wk (CIN x COUT, LDS)
// Lane owns column co for RO nodes. W column hoisted to regs; T rows read
// contiguously so unrolled reads merge into ds_read_b128. Same FMA order
// per acc[i] as the naive version -> bitwise identical.
template<int CIN, int COUT>
__device__ inline void mat_acc(const float* __restrict__ T, const float* __restrict__ Wk,
                               float* __restrict__ acc, int lane) {
    constexpr int RO = COUT / 8;     // outputs (nodes) per lane
    constexpr int NSTEP = 64 / COUT; // node stride per output index
    const int co = lane % COUT;
    const int n0 = lane / COUT;
    float w[CIN];
#pragma unroll
    for (int ci = 0; ci < CIN; ++ci) w[ci] = Wk[ci * COUT + co];
#pragma unroll
    for (int i = 0; i < RO; ++i) {
        const float* Trow = T + (n0 + i * NSTEP) * CIN;
#pragma unroll
        for (int ci = 0; ci < CIN; ++ci) {
            acc[i] = fmaf(Trow[ci], w[ci], acc[i]);
        }
    }
}

// Tout = scale * (L @ Tin) - Tsub   (own-element only; Tin != Tout)
template<int C>
__device__ inline void prop(const float* __restrict__ Tin, float* __restrict__ Tout,
                            const float* __restrict__ L, int lane, float scale,
                            const float* __restrict__ Tsub) {
    constexpr int RI = C / 8;
#pragma unroll
    for (int i = 0; i < RI; ++i) {
        int idx = lane + 64 * i;
        int n = idx / C, c = idx % C;
        float s = 0.f;
#pragma unroll
        for (int k = 0; k < 8; ++k) s = fmaf(L[n * 8 + k], Tin[k * C + c], s);
        float v = scale * s - (Tsub ? Tsub[idx] : 0.f);
        Tout[idx] = v;
    }
}

// One ChebConv layer + bias + relu. Input in S.bufX (8 x CIN).
// BF16OUT=false: out is float* (LDS). BF16OUT=true: out is __hip_bfloat16* (global h3).
template<int CIN, int COUT, bool BF16OUT>
__device__ inline void cheb_layer(WaveScratch& S, const float* __restrict__ sW,
                                  const float* __restrict__ sB, int lane, void* out_p) {
    constexpr int RO = COUT / 8;
    float acc[RO];
    const int co = lane % COUT;
#pragma unroll
    for (int i = 0; i < RO; ++i) acc[i] = sB[co];

    // k=0: T0 = X
    mat_acc<CIN, COUT>(S.bufX, sW, acc, lane);
    prop<CIN>(S.bufX, S.bufT1, S.L, lane, 1.f, nullptr);   // T1 = L X
    __syncthreads();
    // k=1
    mat_acc<CIN, COUT>(S.bufT1, sW + CIN * COUT, acc, lane);
    prop<CIN>(S.bufT1, S.bufT2, S.L, lane, 2.f, S.bufX);   // T2 = 2 L T1 - T0
    __syncthreads();
    // k=2
    mat_acc<CIN, COUT>(S.bufT2, sW + 2 * CIN * COUT, acc, lane);
    prop<CIN>(S.bufT2, S.bufT1, S.L, lane, 2.f, S.bufT1);  // T3 = 2 L T2 - T1 (in place)
    __syncthreads();
    // k=3
    mat_acc<CIN, COUT>(S.bufT1, sW + 3 * CIN * COUT, acc, lane);
    __syncthreads();
    if (BF16OUT) {
        __hip_bfloat16* out = (__hip_bfloat16*)out_p;
#pragma unroll
        for (int i = 0; i < RO; ++i) out[lane + 64 * i] = __float2bfloat16(fmaxf(acc[i], 0.f));
    } else {
        float* out = (float*)out_p;
#pragma unroll
        for (int i = 0; i < RO; ++i) out[lane + 64 * i] = fmaxf(acc[i], 0.f);
    }
    __syncthreads();
}

__global__ __launch_bounds__(256, 2) void cheb_fused(
    const float* __restrict__ x,   // (262144, 8)
    const float* __restrict__ ew,  // (32768*56,)
    const float* __restrict__ w1, const float* __restrict__ b1,
    const float* __restrict__ w2, const float* __restrict__ b2,
    const float* __restrict__ w3, const float* __restrict__ b3,
    __hip_bfloat16* __restrict__ h3)  // (32768, 512) bf16
{
    __shared__ float sW1[4 * 8 * 16];
    __shared__ float sW2[4 * 16 * 32];
    __shared__ float sW3[4 * 32 * 64];
    __shared__ float sB1[16], sB2[32], sB3[64];
    __shared__ WaveScratch ws[4];

    const int t = threadIdx.x;
    for (int i = t; i < 512; i += 256) sW1[i] = w1[i];
    for (int i = t; i < 2048; i += 256) sW2[i] = w2[i];
    for (int i = t; i < 8192; i += 256) sW3[i] = w3[i];
    if (t < 16) sB1[t] = b1[t];
    if (t < 32) sB2[t] = b2[t];
    if (t < 64) sB3[t] = b3[t];

    const int wid = t >> 6, lane = t & 63;
    const int g = blockIdx.x * 4 + wid;
    WaveScratch& S = ws[wid];

    // degree / D^{-1/2}: out-degree over the 7 contiguous out-edges of node s
    if (lane < 8) {
        const float* e = ew + (size_t)g * 56 + lane * 7;
        float d = 0.f;
#pragma unroll
        for (int j = 0; j < 7; ++j) d += e[j];
        S.dis[lane] = rsqrtf(d);
    }
    S.bufX[lane] = x[(size_t)g * 64 + lane];
    __syncthreads();

    // L[d][s] = -dis[s] * w_e * dis[d] for edge e=(s->d); zero diagonal
    if (lane < 56) {
        int s = lane / 7, j = lane % 7;
        int d = j + (j >= s ? 1 : 0);
        float w = ew[(size_t)g * 56 + lane];
        S.L[d * 8 + s] = -S.dis[s] * w * S.dis[d];
    } else {
        S.L[(lane - 56) * 9] = 0.f;
    }
    __syncthreads();

    cheb_layer<8, 16, false>(S, sW1, sB1, lane, S.bufX);
    cheb_layer<16, 32, false>(S, sW2, sB2, lane, S.bufX);
    cheb_layer<32, 64, true>(S, sW3, sB3, lane, h3 + (size_t)g * 512);
}

// ------------------------------------------- weight transpose + bf16 cast
// W (K x N f32, row-major) -> Wt (N x K bf16, row-major). K,N multiples of 32.
__global__ __launch_bounds__(256) void transpose_cast(
    const float* __restrict__ W, __hip_bfloat16* __restrict__ Wt, int K, int N)
{
    __shared__ float tile[32][33];
    const int kb = blockIdx.x * 32, nb = blockIdx.y * 32;
    const int tx = threadIdx.x % 32, ty = threadIdx.x / 32;  // 32 x 8
    for (int i = ty; i < 32; i += 8)
        tile[i][tx] = W[(size_t)(kb + i) * N + nb + tx];
    __syncthreads();
    for (int i = ty; i < 32; i += 8)
        Wt[(size_t)(nb + i) * K + kb + tx] = __float2bfloat16(tile[tx][i]);
}

// --------------------------------------------------- bf16 MFMA FC GEMM
// C = relu(A @ B + bias). A: (M,K) bf16 row-major. Bt: (N,K) bf16 row-major (B^T).
// 128x128 block tile, 4 waves (2x2 of 64x64), 16x16x32 MFMA, BK=32.
template<bool OUT_BF16>
__global__ __launch_bounds__(256) void mfma_fc(
    const __hip_bfloat16* __restrict__ A, const __hip_bfloat16* __restrict__ Bt,
    const float* __restrict__ bias, void* __restrict__ Cout, int M, int N, int K)
{
    __shared__ short As[128][40];  // [row][k], +8 pad: row stride 80B -> 2-way max
    __shared__ short Bs[128][40];  // [col][k]
    const int t = threadIdx.x;
    const int wid = t >> 6, lane = t & 63;
    const int m0 = blockIdx.x * 128, n0 = blockIdx.y * 128;
    const int wm = (wid >> 1) * 64, wn = (wid & 1) * 64;

    const int r_row = t >> 1;          // staging: 2 threads/row
    const int r_k   = (t & 1) * 16;    // each stages 16 contiguous bf16 (2x short8)

    const int fr = lane & 15;          // fragment row/col within 16
    const int kk = (lane >> 4) * 8;    // fragment k-offset

    f32x4 acc[4][4] = {};

    for (int k0 = 0; k0 < K; k0 += 32) {
        short8 av0 = *(const short8*)&A [(size_t)(m0 + r_row) * K + k0 + r_k];
        short8 av1 = *(const short8*)&A [(size_t)(m0 + r_row) * K + k0 + r_k + 8];
        short8 bv0 = *(const short8*)&Bt[(size_t)(n0 + r_row) * K + k0 + r_k];
        short8 bv1 = *(const short8*)&Bt[(size_t)(n0 + r_row) * K + k0 + r_k + 8];
        __syncthreads();  // previous iteration's fragment reads complete
        *(short8*)&As[r_row][r_k]     = av0;
        *(short8*)&As[r_row][r_k + 8] = av1;
        *(short8*)&Bs[r_row][r_k]     = bv0;
        *(short8*)&Bs[r_row][r_k + 8] = bv1;
        __syncthreads();

        short8 af[4], bf[4];
#pragma unroll
        for (int fm = 0; fm < 4; ++fm) af[fm] = *(const short8*)&As[wm + fm * 16 + fr][kk];
#pragma unroll
        for (int fn = 0; fn < 4; ++fn) bf[fn] = *(const short8*)&Bs[wn + fn * 16 + fr][kk];
#pragma unroll
        for (int fm = 0; fm < 4; ++fm)
#pragma unroll
            for (int fn = 0; fn < 4; ++fn)
                acc[fm][fn] = __builtin_amdgcn_mfma_f32_16x16x32_bf16(
                    af[fm], bf[fn], acc[fm][fn], 0, 0, 0);
    }

    const int orow = (lane >> 4) * 4;  // C/D: col = lane&15, row = (lane>>4)*4 + r
#pragma unroll
    for (int fm = 0; fm < 4; ++fm) {
#pragma unroll
        for (int fn = 0; fn < 4; ++fn) {
            const int n = n0 + wn + fn * 16 + fr;
            const float bn = bias[n];
#pragma unroll
            for (int r = 0; r < 4; ++r) {
                const int m = m0 + wm + fm * 16 + orow + r;
                float v = fmaxf(acc[fm][fn][r] + bn, 0.f);
                if (OUT_BF16)
                    ((__hip_bfloat16*)Cout)[(size_t)m * N + n] = __float2bfloat16(v);
                else
                    ((float*)Cout)[(size_t)m * N + n] = v;
            }
        }
    }
}

// ------------------------------------------------- FC3 + log_softmax (fp32)
__global__ __launch_bounds__(256) void fc3_logsoftmax(
    const float* __restrict__ A,  // (32768, 128) f32
    const float* __restrict__ W,  // (128, 5)
    const float* __restrict__ b,
    float* __restrict__ out,      // (32768, 5)
    int M)
{
    __shared__ float sW[128 * 5];
    __shared__ float sB[5];
    const int t = threadIdx.x;
    for (int i = t; i < 640; i += 256) sW[i] = W[i];
    if (t < 5) sB[t] = b[t];
    __syncthreads();

    int row = blockIdx.x * blockDim.x + t;
    if (row >= M) return;
    float logits[5];
#pragma unroll
    for (int j = 0; j < 5; ++j) logits[j] = sB[j];
    const float* a = A + (size_t)row * 128;
    for (int k = 0; k < 128; k += 4) {
        float4 av = *(const float4*)&a[k];
        const float* wk = sW + k * 5;
#pragma unroll
        for (int j = 0; j < 5; ++j) logits[j] = fmaf(av.x, wk[j], logits[j]);
#pragma unroll
        for (int j = 0; j < 5; ++j) logits[j] = fmaf(av.y, wk[5 + j], logits[j]);
#pragma unroll
        for (int j = 0; j < 5; ++j) logits[j] = fmaf(av.z, wk[10 + j], logits[j]);
#pragma unroll
        for (int j = 0; j < 5; ++j) logits[j] = fmaf(av.w, wk[15 + j], logits[j]);
    }
    float mx = logits[0];
#pragma unroll
    for (int j = 1; j < 5; ++j) mx = fmaxf(mx, logits[j]);
    float s = 0.f;
#pragma unroll
    for (int j = 0; j < 5; ++j) s += expf(logits[j] - mx);
    float lse = mx + logf(s);
#pragma unroll
    for (int j = 0; j < 5; ++j) out[(size_t)row * 5 + j] = logits[j] - lse;
}

extern "C" void kernel_launch(void* const* d_in, const int* in_sizes, int n_in,
                              void* d_out, int out_size, void* d_ws, size_t ws_size,
                              hipStream_t stream) {
    const float* x     = (const float*)d_in[0];
    // d_in[1], d_in[2]: edge_src/edge_dst — structure is static, unused
    const float* ew    = (const float*)d_in[3];
    const float* w1    = (const float*)d_in[4];
    const float* b1    = (const float*)d_in[5];
    const float* w2    = (const float*)d_in[6];
    const float* b2    = (const float*)d_in[7];
    const float* w3    = (const float*)d_in[8];
    const float* b3    = (const float*)d_in[9];
    const float* fc1_w = (const float*)d_in[10];
    const float* fc1_b = (const float*)d_in[11];
    const float* fc2_w = (const float*)d_in[12];
    const float* fc2_b = (const float*)d_in[13];
    const float* fc3_w = (const float*)d_in[14];
    const float* fc3_b = (const float*)d_in[15];
    float* out = (float*)d_out;

    // ws layout (bytes):
    //   h3  bf16 32768x512  = 32 MB
    //   a1  bf16 32768x256  = 16 MB
    //   a2  f32  32768x128  = 16 MB
    //   Wt1 bf16 256x512    = 256 KB
    //   Wt2 bf16 128x256    = 64 KB          total ~64.3 MB
    char* p = (char*)d_ws;
    __hip_bfloat16* h3  = (__hip_bfloat16*)p;                 p += (size_t)NGRAPH * 512 * 2;
    __hip_bfloat16* a1  = (__hip_bfloat16*)p;                 p += (size_t)NGRAPH * 256 * 2;
    float*          a2  = (float*)p;                          p += (size_t)NGRAPH * 128 * 4;
    __hip_bfloat16* Wt1 = (__hip_bfloat16*)p;                 p += (size_t)256 * 512 * 2;
    __hip_bfloat16* Wt2 = (__hip_bfloat16*)p;

    transpose_cast<<<dim3(512 / 32, 256 / 32), 256, 0, stream>>>(fc1_w, Wt1, 512, 256);
    transpose_cast<<<dim3(256 / 32, 128 / 32), 256, 0, stream>>>(fc2_w, Wt2, 256, 128);
    cheb_fused<<<NGRAPH / 4, 256, 0, stream>>>(x, ew, w1, b1, w2, b2, w3, b3, h3);
    mfma_fc<true ><<<dim3(NGRAPH / 128, 256 / 128), 256, 0, stream>>>(h3, Wt1, fc1_b, a1,
                                                                      NGRAPH, 256, 512);
    mfma_fc<false><<<dim3(NGRAPH / 128, 128 / 128), 256, 0, stream>>>(a1, Wt2, fc2_b, a2,
                                                                      NGRAPH, 128, 256);
    fc3_logsoftmax<<<NGRAPH / 256, 256, 0, stream>>>(a2, fc3_w, fc3_b, out, NGRAPH);
}

// Round 6
// 225.920 us; speedup vs baseline: 1.5316x; 1.5316x over previous
//
#include <hip/hip_runtime.h>
#include <hip/hip_bf16.h>
#include <math.h>

// Problem constants (structure is static per the reference):
//   B=32768 graphs, 8 nodes/graph, fully-connected no-self-loop => 56 edges/graph
//   K=4 Chebyshev, channels 8 -> 16 -> 32 -> 64, MLP 512->256->128->5, log_softmax
#define NGRAPH 32768

typedef __attribute__((ext_vector_type(8))) short short8;
typedef __attribute__((ext_vector_type(4))) float f32x4;

__device__ inline short f2bf(float f) {
    __hip_bfloat16 h = __float2bfloat16(f);
    return *reinterpret_cast<short*>(&h);
}

// ---------------------------------------------------------------- cheb stack
struct WaveScratch {
    float L[64];      // 8x8 scaled Laplacian, L[d*8+s]
    float dis[8];     // D^{-1/2}
    float bufX[256];  // current layer input (8 x C_in), also layer output
    float bufT1[256];
    float bufT2[256];
};

// acc += T (8 x CIN, LDS, node-major) @ Wk (CIN x COUT, LDS)  [layer 1 only now]
template<int CIN, int COUT>
__device__ inline void mat_acc(const float* __restrict__ T, const float* __restrict__ Wk,
                               float* __restrict__ acc, int lane) {
    constexpr int RO = COUT / 8;
    constexpr int NSTEP = 64 / COUT;
    const int co = lane % COUT;
    const int n0 = lane / COUT;
    float w[CIN];
#pragma unroll
    for (int ci = 0; ci < CIN; ++ci) w[ci] = Wk[ci * COUT + co];
#pragma unroll
    for (int i = 0; i < RO; ++i) {
        const float* Trow = T + (n0 + i * NSTEP) * CIN;
#pragma unroll
        for (int ci = 0; ci < CIN; ++ci) acc[i] = fmaf(Trow[ci], w[ci], acc[i]);
    }
}

// Tout = scale * (L @ Tin) - Tsub   (own-element only; Tin != Tout)
template<int C>
__device__ inline void prop(const float* __restrict__ Tin, float* __restrict__ Tout,
                            const float* __restrict__ L, int lane, float scale,
                            const float* __restrict__ Tsub) {
    constexpr int RI = C / 8;
#pragma unroll
    for (int i = 0; i < RI; ++i) {
        int idx = lane + 64 * i;
        int n = idx / C, c = idx % C;
        float s = 0.f;
#pragma unroll
        for (int k = 0; k < 8; ++k) s = fmaf(L[n * 8 + k], Tin[k * C + c], s);
        Tout[idx] = scale * s - (Tsub ? Tsub[idx] : 0.f);
    }
}

// Stage T (8 x C fp32, per-wave) into block A-matrix as bf16: At[wid*8+n][k*C+c]
template<int C>
__device__ inline void stage_T(const float* __restrict__ T, short At[32][136],
                               int wid, int lane, int k) {
    constexpr int RI = C * 8 / 64;
#pragma unroll
    for (int i = 0; i < RI; ++i) {
        int idx = lane + 64 * i;
        int n = idx / C, c = idx % C;
        At[wid * 8 + n][k * C + c] = f2bf(T[idx]);
    }
}

// Layer 1 (8->16), full fp32 VALU, output into S.bufX (8x16)
__device__ inline void cheb_layer1(WaveScratch& S, const float* __restrict__ sW,
                                   const float* __restrict__ sB, int lane) {
    float acc[2];
    const int co = lane % 16;
#pragma unroll
    for (int i = 0; i < 2; ++i) acc[i] = sB[co];
    mat_acc<8, 16>(S.bufX, sW, acc, lane);
    prop<8>(S.bufX, S.bufT1, S.L, lane, 1.f, nullptr);
    __syncthreads();
    mat_acc<8, 16>(S.bufT1, sW + 128, acc, lane);
    prop<8>(S.bufT1, S.bufT2, S.L, lane, 2.f, S.bufX);
    __syncthreads();
    mat_acc<8, 16>(S.bufT2, sW + 256, acc, lane);
    prop<8>(S.bufT2, S.bufT1, S.L, lane, 2.f, S.bufT1);
    __syncthreads();
    mat_acc<8, 16>(S.bufT1, sW + 384, acc, lane);
    __syncthreads();
#pragma unroll
    for (int i = 0; i < 2; ++i) S.bufX[lane + 64 * i] = fmaxf(acc[i], 0.f);
    __syncthreads();
}

__global__ __launch_bounds__(256, 3) void cheb_fused(
    const float* __restrict__ x,   // (262144, 8)
    const float* __restrict__ ew,  // (32768*56,)
    const float* __restrict__ w1, const float* __restrict__ b1,
    const float* __restrict__ w2, const float* __restrict__ b2,
    const float* __restrict__ w3, const float* __restrict__ b3,
    __hip_bfloat16* __restrict__ h3)  // (32768, 512) bf16
{
    __shared__ float sW1[512];
    __shared__ float sB1[16], sB2[32], sB3[64];
    __shared__ short W2t[32][72];    // W2^T bf16: [co][k*16+ci], pad->conflict-free frags
    __shared__ short W3t[64][136];   // W3^T bf16: [co][k*32+ci]
    __shared__ short At[32][136];    // block A-matrix bf16: [graph*8+node][k*CIN+ci]
    __shared__ WaveScratch ws[4];

    const int t = threadIdx.x;
    for (int i = t; i < 512; i += 256) sW1[i] = w1[i];
    // w2 flat idx = (k*16+ci)*32 + co  ->  W2t[co][k*16+ci]
    for (int i = t; i < 2048; i += 256) W2t[i & 31][i >> 5] = f2bf(w2[i]);
    // w3 flat idx = (k*32+ci)*64 + co  ->  W3t[co][k*32+ci]
    for (int i = t; i < 8192; i += 256) W3t[i & 63][i >> 6] = f2bf(w3[i]);
    if (t < 16) sB1[t] = b1[t];
    if (t < 32) sB2[t] = b2[t];
    if (t < 64) sB3[t] = b3[t];

    const int wid = t >> 6, lane = t & 63;
    const int g = blockIdx.x * 4 + wid;
    WaveScratch& S = ws[wid];

    // degree / D^{-1/2}: out-degree over the 7 contiguous out-edges of node s
    if (lane < 8) {
        const float* e = ew + (size_t)g * 56 + lane * 7;
        float d = 0.f;
#pragma unroll
        for (int j = 0; j < 7; ++j) d += e[j];
        S.dis[lane] = rsqrtf(d);
    }
    S.bufX[lane] = x[(size_t)g * 64 + lane];
    __syncthreads();

    // L[d][s] = -dis[s] * w_e * dis[d] for edge e=(s->d); zero diagonal
    if (lane < 56) {
        int s = lane / 7, j = lane % 7;
        int d = j + (j >= s ? 1 : 0);
        float w = ew[(size_t)g * 56 + lane];
        S.L[d * 8 + s] = -S.dis[s] * w * S.dis[d];
    } else {
        S.L[(lane - 56) * 9] = 0.f;
    }
    __syncthreads();

    // ---------------- layer 1 (8->16): fp32 VALU ----------------
    cheb_layer1(S, sW1, sB1, lane);

    // ---------------- layer 2 (16->32): fp32 recurrence + MFMA ----------------
    stage_T<16>(S.bufX, At, wid, lane, 0);
    prop<16>(S.bufX, S.bufT1, S.L, lane, 1.f, nullptr);
    stage_T<16>(S.bufT1, At, wid, lane, 1);
    prop<16>(S.bufT1, S.bufT2, S.L, lane, 2.f, S.bufX);
    stage_T<16>(S.bufT2, At, wid, lane, 2);
    prop<16>(S.bufT2, S.bufT1, S.L, lane, 2.f, S.bufT1);
    stage_T<16>(S.bufT1, At, wid, lane, 3);
    __syncthreads();
    {
        const int mt = wid >> 1, nt = wid & 1;   // 2 M-tiles x 2 N-tiles
        const int fr = lane & 15, kk = (lane >> 4) * 8;
        f32x4 acc = {};
#pragma unroll
        for (int kk0 = 0; kk0 < 64; kk0 += 32) {
            short8 a = *(const short8*)&At [mt * 16 + fr][kk0 + kk];
            short8 b = *(const short8*)&W2t[nt * 16 + fr][kk0 + kk];
            acc = __builtin_amdgcn_mfma_f32_16x16x32_bf16(a, b, acc, 0, 0, 0);
        }
        __syncthreads();  // At reads done before layer-3 staging rewrites it
#pragma unroll
        for (int r = 0; r < 4; ++r) {
            int R = mt * 16 + (lane >> 4) * 4 + r;  // block row = graph*8+node
            int n = nt * 16 + fr;
            ws[R >> 3].bufX[(R & 7) * 32 + n] = fmaxf(acc[r] + sB2[n], 0.f);
        }
        __syncthreads();
    }

    // ---------------- layer 3 (32->64): fp32 recurrence + MFMA ----------------
    stage_T<32>(S.bufX, At, wid, lane, 0);
    prop<32>(S.bufX, S.bufT1, S.L, lane, 1.f, nullptr);
    stage_T<32>(S.bufT1, At, wid, lane, 1);
    prop<32>(S.bufT1, S.bufT2, S.L, lane, 2.f, S.bufX);
    stage_T<32>(S.bufT2, At, wid, lane, 2);
    prop<32>(S.bufT2, S.bufT1, S.L, lane, 2.f, S.bufT1);
    stage_T<32>(S.bufT1, At, wid, lane, 3);
    __syncthreads();
    {
        const int mt = wid >> 1;                  // 2 M-tiles x 4 N-tiles, 2 nt per wave
        const int nt0 = (wid & 1) * 2;
        const int fr = lane & 15, kk = (lane >> 4) * 8;
        f32x4 acc0 = {}, acc1 = {};
#pragma unroll
        for (int kk0 = 0; kk0 < 128; kk0 += 32) {
            short8 a  = *(const short8*)&At [mt * 16 + fr][kk0 + kk];
            short8 b0 = *(const short8*)&W3t[nt0 * 16 + fr][kk0 + kk];
            short8 b1 = *(const short8*)&W3t[(nt0 + 1) * 16 + fr][kk0 + kk];
            acc0 = __builtin_amdgcn_mfma_f32_16x16x32_bf16(a, b0, acc0, 0, 0, 0);
            acc1 = __builtin_amdgcn_mfma_f32_16x16x32_bf16(a, b1, acc1, 0, 0, 0);
        }
        const int gbase = blockIdx.x * 4;
#pragma unroll
        for (int r = 0; r < 4; ++r) {
            int R = mt * 16 + (lane >> 4) * 4 + r;
            size_t base = (size_t)(gbase + (R >> 3)) * 512 + (R & 7) * 64;
            int n0 = nt0 * 16 + fr;
            h3[base + n0]      = __float2bfloat16(fmaxf(acc0[r] + sB3[n0], 0.f));
            h3[base + n0 + 16] = __float2bfloat16(fmaxf(acc1[r] + sB3[n0 + 16], 0.f));
        }
    }
}

// ------------------------------------------- weight transpose + bf16 cast
// W (K x N f32, row-major) -> Wt (N x K bf16, row-major). K,N multiples of 32.
__global__ __launch_bounds__(256) void transpose_cast(
    const float* __restrict__ W, __hip_bfloat16* __restrict__ Wt, int K, int N)
{
    __shared__ float tile[32][33];
    const int kb = blockIdx.x * 32, nb = blockIdx.y * 32;
    const int tx = threadIdx.x % 32, ty = threadIdx.x / 32;  // 32 x 8
    for (int i = ty; i < 32; i += 8)
        tile[i][tx] = W[(size_t)(kb + i) * N + nb + tx];
    __syncthreads();
    for (int i = ty; i < 32; i += 8)
        Wt[(size_t)(nb + i) * K + kb + tx] = __float2bfloat16(tile[tx][i]);
}

// --------------------------------------------------- bf16 MFMA FC GEMM
// C = relu(A @ B + bias). A: (M,K) bf16 row-major. Bt: (N,K) bf16 row-major (B^T).
// 128x128 block tile, 4 waves (2x2 of 64x64), 16x16x32 MFMA, BK=32.
template<bool OUT_BF16>
__global__ __launch_bounds__(256) void mfma_fc(
    const __hip_bfloat16* __restrict__ A, const __hip_bfloat16* __restrict__ Bt,
    const float* __restrict__ bias, void* __restrict__ Cout, int M, int N, int K)
{
    __shared__ short As[128][40];  // [row][k], +8 pad: row stride 80B -> 2-way max
    __shared__ short Bs[128][40];  // [col][k]
    const int t = threadIdx.x;
    const int wid = t >> 6, lane = t & 63;
    const int m0 = blockIdx.x * 128, n0 = blockIdx.y * 128;
    const int wm = (wid >> 1) * 64, wn = (wid & 1) * 64;

    const int r_row = t >> 1;          // staging: 2 threads/row
    const int r_k   = (t & 1) * 16;    // each stages 16 contiguous bf16 (2x short8)

    const int fr = lane & 15;          // fragment row/col within 16
    const int kk = (lane >> 4) * 8;    // fragment k-offset

    f32x4 acc[4][4] = {};

    for (int k0 = 0; k0 < K; k0 += 32) {
        short8 av0 = *(const short8*)&A [(size_t)(m0 + r_row) * K + k0 + r_k];
        short8 av1 = *(const short8*)&A [(size_t)(m0 + r_row) * K + k0 + r_k + 8];
        short8 bv0 = *(const short8*)&Bt[(size_t)(n0 + r_row) * K + k0 + r_k];
        short8 bv1 = *(const short8*)&Bt[(size_t)(n0 + r_row) * K + k0 + r_k + 8];
        __syncthreads();  // previous iteration's fragment reads complete
        *(short8*)&As[r_row][r_k]     = av0;
        *(short8*)&As[r_row][r_k + 8] = av1;
        *(short8*)&Bs[r_row][r_k]     = bv0;
        *(short8*)&Bs[r_row][r_k + 8] = bv1;
        __syncthreads();

        short8 af[4], bf[4];
#pragma unroll
        for (int fm = 0; fm < 4; ++fm) af[fm] = *(const short8*)&As[wm + fm * 16 + fr][kk];
#pragma unroll
        for (int fn = 0; fn < 4; ++fn) bf[fn] = *(const short8*)&Bs[wn + fn * 16 + fr][kk];
#pragma unroll
        for (int fm = 0; fm < 4; ++fm)
#pragma unroll
            for (int fn = 0; fn < 4; ++fn)
                acc[fm][fn] = __builtin_amdgcn_mfma_f32_16x16x32_bf16(
                    af[fm], bf[fn], acc[fm][fn], 0, 0, 0);
    }

    const int orow = (lane >> 4) * 4;  // C/D: col = lane&15, row = (lane>>4)*4 + r
#pragma unroll
    for (int fm = 0; fm < 4; ++fm) {
#pragma unroll
        for (int fn = 0; fn < 4; ++fn) {
            const int n = n0 + wn + fn * 16 + fr;
            const float bn = bias[n];
#pragma unroll
            for (int r = 0; r < 4; ++r) {
                const int m = m0 + wm + fm * 16 + orow + r;
                float v = fmaxf(acc[fm][fn][r] + bn, 0.f);
                if (OUT_BF16)
                    ((__hip_bfloat16*)Cout)[(size_t)m * N + n] = __float2bfloat16(v);
                else
                    ((float*)Cout)[(size_t)m * N + n] = v;
            }
        }
    }
}

// ------------------------------------------------- FC3 + log_softmax (fp32)
__global__ __launch_bounds__(256) void fc3_logsoftmax(
    const float* __restrict__ A,  // (32768, 128) f32
    const float* __restrict__ W,  // (128, 5)
    const float* __restrict__ b,
    float* __restrict__ out,      // (32768, 5)
    int M)
{
    __shared__ float sW[128 * 5];
    __shared__ float sB[5];
    const int t = threadIdx.x;
    for (int i = t; i < 640; i += 256) sW[i] = W[i];
    if (t < 5) sB[t] = b[t];
    __syncthreads();

    int row = blockIdx.x * blockDim.x + t;
    if (row >= M) return;
    float logits[5];
#pragma unroll
    for (int j = 0; j < 5; ++j) logits[j] = sB[j];
    const float* a = A + (size_t)row * 128;
    for (int k = 0; k < 128; k += 4) {
        float4 av = *(const float4*)&a[k];
        const float* wk = sW + k * 5;
#pragma unroll
        for (int j = 0; j < 5; ++j) logits[j] = fmaf(av.x, wk[j], logits[j]);
#pragma unroll
        for (int j = 0; j < 5; ++j) logits[j] = fmaf(av.y, wk[5 + j], logits[j]);
#pragma unroll
        for (int j = 0; j < 5; ++j) logits[j] = fmaf(av.z, wk[10 + j], logits[j]);
#pragma unroll
        for (int j = 0; j < 5; ++j) logits[j] = fmaf(av.w, wk[15 + j], logits[j]);
    }
    float mx = logits[0];
#pragma unroll
    for (int j = 1; j < 5; ++j) mx = fmaxf(mx, logits[j]);
    float s = 0.f;
#pragma unroll
    for (int j = 0; j < 5; ++j) s += expf(logits[j] - mx);
    float lse = mx + logf(s);
#pragma unroll
    for (int j = 0; j < 5; ++j) out[(size_t)row * 5 + j] = logits[j] - lse;
}

extern "C" void kernel_launch(void* const* d_in, const int* in_sizes, int n_in,
                              void* d_out, int out_size, void* d_ws, size_t ws_size,
                              hipStream_t stream) {
    const float* x     = (const float*)d_in[0];
    // d_in[1], d_in[2]: edge_src/edge_dst — structure is static, unused
    const float* ew    = (const float*)d_in[3];
    const float* w1    = (const float*)d_in[4];
    const float* b1    = (const float*)d_in[5];
    const float* w2    = (const float*)d_in[6];
    const float* b2    = (const float*)d_in[7];
    const float* w3    = (const float*)d_in[8];
    const float* b3    = (const float*)d_in[9];
    const float* fc1_w = (const float*)d_in[10];
    const float* fc1_b = (const float*)d_in[11];
    const float* fc2_w = (const float*)d_in[12];
    const float* fc2_b = (const float*)d_in[13];
    const float* fc3_w = (const float*)d_in[14];
    const float* fc3_b = (const float*)d_in[15];
    float* out = (float*)d_out;

    // ws layout (bytes):
    //   h3  bf16 32768x512  = 32 MB
    //   a1  bf16 32768x256  = 16 MB
    //   a2  f32  32768x128  = 16 MB
    //   Wt1 bf16 256x512    = 256 KB
    //   Wt2 bf16 128x256    = 64 KB          total ~64.3 MB
    char* p = (char*)d_ws;
    __hip_bfloat16* h3  = (__hip_bfloat16*)p;                 p += (size_t)NGRAPH * 512 * 2;
    __hip_bfloat16* a1  = (__hip_bfloat16*)p;                 p += (size_t)NGRAPH * 256 * 2;
    float*          a2  = (float*)p;                          p += (size_t)NGRAPH * 128 * 4;
    __hip_bfloat16* Wt1 = (__hip_bfloat16*)p;                 p += (size_t)256 * 512 * 2;
    __hip_bfloat16* Wt2 = (__hip_bfloat16*)p;

    transpose_cast<<<dim3(512 / 32, 256 / 32), 256, 0, stream>>>(fc1_w, Wt1, 512, 256);
    transpose_cast<<<dim3(256 / 32, 128 / 32), 256, 0, stream>>>(fc2_w, Wt2, 256, 128);
    cheb_fused<<<NGRAPH / 4, 256, 0, stream>>>(x, ew, w1, b1, w2, b2, w3, b3, h3);
    mfma_fc<true ><<<dim3(NGRAPH / 128, 256 / 128), 256, 0, stream>>>(h3, Wt1, fc1_b, a1,
                                                                      NGRAPH, 256, 512);
    mfma_fc<false><<<dim3(NGRAPH / 128, 128 / 128), 256, 0, stream>>>(a1, Wt2, fc2_b, a2,
                                                                      NGRAPH, 128, 256);
    fc3_logsoftmax<<<NGRAPH / 256, 256, 0, stream>>>(a2, fc3_w, fc3_b, out, NGRAPH);
}

// Round 8
// 187.094 us; speedup vs baseline: 1.8494x; 1.2075x over previous
//
#include <hip/hip_runtime.h>
#include <hip/hip_bf16.h>
#include <math.h>

// B=32768 graphs, 8 nodes/graph, fully-connected no-self-loop => 56 edges/graph
// K=4 Chebyshev, channels 8 -> 16 -> 32 -> 64, MLP 512->256->128->5, log_softmax
#define NGRAPH 32768

typedef __attribute__((ext_vector_type(8))) short short8;
typedef __attribute__((ext_vector_type(4))) float f32x4;

__device__ inline short f2bf(float f) {
    __hip_bfloat16 h = __float2bfloat16(f);
    return *reinterpret_cast<short*>(&h);
}

// ---------------------------------------------------------------- cheb stack
// Per-wave scratch. T stored CHANNEL-MAJOR (Tt[c][n]) so prop reads are
// float4 rows with 8-lane broadcast. Recurrence stays pure fp32.
struct __align__(16) WaveScratch {
    float L[8][8];       // scaled Laplacian, L[nout][nin]; rows 32B, 16B-aligned
    float dis[8];
    float Tt[2][32][8];  // ping-pong Chebyshev states, [buf][channel][node]
};

// T_k for k=1..3: T1 = L@T0; Tk = 2 L@T_{k-1} - T_{k-2}.
// Writes fp32 into Tt ping-pong AND bf16 into At[wid*8+n][k*CIN+c].
template<int CIN>
__device__ inline void props3(WaveScratch& S, short (*At)[136], int wid, int lane) {
    const int n = lane & 7, cb0 = lane >> 3;
#pragma unroll
    for (int k = 1; k <= 3; ++k) {
        const int pp = (k + 1) & 1;  // buffer holding T_{k-1}
#pragma unroll
        for (int i = 0; i < CIN / 8; ++i) {
            const int c = cb0 + 8 * i;
            float4 l0 = *(const float4*)&S.L[n][0];
            float4 l1 = *(const float4*)&S.L[n][4];
            float4 t0 = *(const float4*)&S.Tt[pp][c][0];
            float4 t1 = *(const float4*)&S.Tt[pp][c][4];
            float s = l0.x * t0.x;
            s = fmaf(l0.y, t0.y, s); s = fmaf(l0.z, t0.z, s); s = fmaf(l0.w, t0.w, s);
            s = fmaf(l1.x, t1.x, s); s = fmaf(l1.y, t1.y, s);
            s = fmaf(l1.z, t1.z, s); s = fmaf(l1.w, t1.w, s);
            float v = (k == 1) ? s : fmaf(2.f, s, -S.Tt[pp ^ 1][c][n]);
            S.Tt[pp ^ 1][c][n] = v;                 // own-element overwrite of T_{k-2}
            At[wid * 8 + n][k * CIN + c] = f2bf(v);
        }
    }
}

// Load one MFMA B-fragment (8 bf16) for output column co from row-major W (K x COUT).
__device__ inline short8 load_bfrag(const float* __restrict__ W, int COUT, int co, int kb) {
    short8 r;
#pragma unroll
    for (int j = 0; j < 8; ++j) r[j] = f2bf(W[(size_t)(kb + j) * COUT + co]);
    return r;
}

__global__ __launch_bounds__(256, 3) void cheb_fused(
    const float* __restrict__ x,   // (262144, 8)
    const float* __restrict__ ew,  // (32768*56,)
    const float* __restrict__ w1, const float* __restrict__ b1,
    const float* __restrict__ w2, const float* __restrict__ b2,
    const float* __restrict__ w3, const float* __restrict__ b3,
    __hip_bfloat16* __restrict__ h3)  // (32768, 512) bf16
{
    __shared__ WaveScratch ws[4];
    __shared__ short At[32][136];    // block A-matrix bf16: [graph*8+node][k*CIN+c]
    __shared__ float sB1[16], sB2[32], sB3[64];

    const int t = threadIdx.x;
    const int wid = t >> 6, lane = t & 63;
    const int fr = lane & 15;          // MFMA fragment row/col within 16
    const int kk = (lane >> 4) * 8;    // MFMA fragment k-offset (shorts)
    const int q  = lane >> 4;

    if (t < 16) sB1[t] = b1[t];
    if (t < 32) sB2[t] = b2[t];
    if (t < 64) sB3[t] = b3[t];

    // ---- preload MFMA B-fragments of cheb weights into registers (L2-broadcast)
    short8 W1f = {};
    if (wid < 2) W1f = load_bfrag(w1, 16, fr, kk);
    short8 W2f[2];
    {
        const int nt = wid & 1;
#pragma unroll
        for (int s = 0; s < 2; ++s) W2f[s] = load_bfrag(w2, 32, nt * 16 + fr, s * 32 + kk);
    }
    short8 W3f[2][4];
    {
        const int nt0 = (wid & 1) * 2;
#pragma unroll
        for (int tt = 0; tt < 2; ++tt)
#pragma unroll
            for (int s = 0; s < 4; ++s)
                W3f[tt][s] = load_bfrag(w3, 64, (nt0 + tt) * 16 + fr, s * 32 + kk);
    }

    const int g = blockIdx.x * 4 + wid;
    WaveScratch& S = ws[wid];

    // ---- degree / D^{-1/2} (intra-wave only; compiler orders LDS deps)
    if (lane < 8) {
        const float* e = ew + (size_t)g * 56 + lane * 7;
        float d = 0.f;
#pragma unroll
        for (int j = 0; j < 7; ++j) d += e[j];
        S.dis[lane] = rsqrtf(d);
    }
    // ---- stage X: x row-major (n,c) -> Tt[0][c][n] fp32 + At[.][c] bf16
    {
        float xv = x[(size_t)g * 64 + lane];
        int n = lane >> 3, c = lane & 7;
        S.Tt[0][c][n] = xv;
        At[wid * 8 + n][c] = f2bf(xv);
    }
    // ---- L[d][s] = -dis[s]*w*dis[d]; zero diagonal
    if (lane < 56) {
        int s = lane / 7, j = lane % 7;
        int d = j + (j >= s ? 1 : 0);
        float w = ew[(size_t)g * 56 + lane];
        S.L[d][s] = -S.dis[s] * w * S.dis[d];
    } else if (lane < 64) {
        S.L[lane - 56][lane - 56] = 0.f;
    }

    // ================= layer 1 (8 -> 16) =================
    props3<8>(S, At, wid, lane);
    __syncthreads();                       // At[.][0:32] complete (all graphs)
    if (wid < 2) {
        const int mt = wid;
        f32x4 acc = {};
        short8 a = *(const short8*)&At[mt * 16 + fr][kk];
        acc = __builtin_amdgcn_mfma_f32_16x16x32_bf16(a, W1f, acc, 0, 0, 0);
        float vr[4];
#pragma unroll
        for (int r = 0; r < 4; ++r) vr[r] = fmaxf(acc[r] + sB1[fr], 0.f);
        // layer-2 T0: fragment rows R=mt*16+q*4+r are nodes (q&1)*4+r of graph mt*2+(q>>1)
        *(float4*)&ws[mt * 2 + (q >> 1)].Tt[0][fr][(q & 1) * 4] =
            float4{vr[0], vr[1], vr[2], vr[3]};
#pragma unroll
        for (int r = 0; r < 4; ++r) At[mt * 16 + q * 4 + r][fr] = f2bf(vr[r]);
    }
    __syncthreads();                       // cross-wave Tt[0]/At T0 ready

    // ================= layer 2 (16 -> 32) =================
    props3<16>(S, At, wid, lane);
    __syncthreads();
    {
        const int mt = wid >> 1, nt = wid & 1;
        f32x4 acc = {};
#pragma unroll
        for (int s = 0; s < 2; ++s) {
            short8 a = *(const short8*)&At[mt * 16 + fr][s * 32 + kk];
            acc = __builtin_amdgcn_mfma_f32_16x16x32_bf16(a, W2f[s], acc, 0, 0, 0);
        }
        const int col = nt * 16 + fr;
        float vr[4];
#pragma unroll
        for (int r = 0; r < 4; ++r) vr[r] = fmaxf(acc[r] + sB2[col], 0.f);
        *(float4*)&ws[mt * 2 + (q >> 1)].Tt[0][col][(q & 1) * 4] =
            float4{vr[0], vr[1], vr[2], vr[3]};
#pragma unroll
        for (int r = 0; r < 4; ++r) At[mt * 16 + q * 4 + r][col] = f2bf(vr[r]);
    }
    __syncthreads();

    // ================= layer 3 (32 -> 64) =================
    props3<32>(S, At, wid, lane);
    __syncthreads();
    {
        const int mt = wid >> 1, nt0 = (wid & 1) * 2;
        f32x4 acc0 = {}, acc1 = {};
#pragma unroll
        for (int s = 0; s < 4; ++s) {
            short8 a = *(const short8*)&At[mt * 16 + fr][s * 32 + kk];
            acc0 = __builtin_amdgcn_mfma_f32_16x16x32_bf16(a, W3f[0][s], acc0, 0, 0, 0);
            acc1 = __builtin_amdgcn_mfma_f32_16x16x32_bf16(a, W3f[1][s], acc1, 0, 0, 0);
        }
        const int gbase = blockIdx.x * 4;
        const int c0 = nt0 * 16 + fr;
#pragma unroll
        for (int r = 0; r < 4; ++r) {
            int R = mt * 16 + q * 4 + r;
            size_t base = (size_t)(gbase + (R >> 3)) * 512 + (R & 7) * 64;
            h3[base + c0]      = __float2bfloat16(fmaxf(acc0[r] + sB3[c0], 0.f));
            h3[base + c0 + 16] = __float2bfloat16(fmaxf(acc1[r] + sB3[c0 + 16], 0.f));
        }
    }
}

// ------------------------------------------- weight transpose + bf16 cast (FC)
// W (K x N f32, row-major) -> Wt (N x K bf16, row-major). K,N multiples of 32.
__global__ __launch_bounds__(256) void transpose_cast(
    const float* __restrict__ W, __hip_bfloat16* __restrict__ Wt, int K, int N)
{
    __shared__ float tile[32][33];
    const int kb = blockIdx.x * 32, nb = blockIdx.y * 32;
    const int tx = threadIdx.x % 32, ty = threadIdx.x / 32;  // 32 x 8
    for (int i = ty; i < 32; i += 8)
        tile[i][tx] = W[(size_t)(kb + i) * N + nb + tx];
    __syncthreads();
    for (int i = ty; i < 32; i += 8)
        Wt[(size_t)(nb + i) * K + kb + tx] = __float2bfloat16(tile[tx][i]);
}

// --------------------------------------------------- bf16 MFMA FC GEMM
// C = relu(A @ B + bias). A: (M,K) bf16 row-major. Bt: (N,K) bf16 row-major (B^T).
// 128x128 block tile, 4 waves (2x2 of 64x64), 16x16x32 MFMA, BK=32.
template<bool OUT_BF16>
__global__ __launch_bounds__(256) void mfma_fc(
    const __hip_bfloat16* __restrict__ A, const __hip_bfloat16* __restrict__ Bt,
    const float* __restrict__ bias, void* __restrict__ Cout, int M, int N, int K)
{
    __shared__ short As[128][40];  // [row][k], +8 pad: row stride 80B -> 2-way max
    __shared__ short Bs[128][40];  // [col][k]
    const int t = threadIdx.x;
    const int wid = t >> 6, lane = t & 63;
    const int m0 = blockIdx.x * 128, n0 = blockIdx.y * 128;
    const int wm = (wid >> 1) * 64, wn = (wid & 1) * 64;

    const int r_row = t >> 1;          // staging: 2 threads/row
    const int r_k   = (t & 1) * 16;    // each stages 16 contiguous bf16 (2x short8)

    const int fr = lane & 15;          // fragment row/col within 16
    const int kk = (lane >> 4) * 8;    // fragment k-offset

    f32x4 acc[4][4] = {};

    for (int k0 = 0; k0 < K; k0 += 32) {
        short8 av0 = *(const short8*)&A [(size_t)(m0 + r_row) * K + k0 + r_k];
        short8 av1 = *(const short8*)&A [(size_t)(m0 + r_row) * K + k0 + r_k + 8];
        short8 bv0 = *(const short8*)&Bt[(size_t)(n0 + r_row) * K + k0 + r_k];
        short8 bv1 = *(const short8*)&Bt[(size_t)(n0 + r_row) * K + k0 + r_k + 8];
        __syncthreads();  // previous iteration's fragment reads complete
        *(short8*)&As[r_row][r_k]     = av0;
        *(short8*)&As[r_row][r_k + 8] = av1;
        *(short8*)&Bs[r_row][r_k]     = bv0;
        *(short8*)&Bs[r_row][r_k + 8] = bv1;
        __syncthreads();

        short8 af[4], bf[4];
#pragma unroll
        for (int fm = 0; fm < 4; ++fm) af[fm] = *(const short8*)&As[wm + fm * 16 + fr][kk];
#pragma unroll
        for (int fn = 0; fn < 4; ++fn) bf[fn] = *(const short8*)&Bs[wn + fn * 16 + fr][kk];
#pragma unroll
        for (int fm = 0; fm < 4; ++fm)
#pragma unroll
            for (int fn = 0; fn < 4; ++fn)
                acc[fm][fn] = __builtin_amdgcn_mfma_f32_16x16x32_bf16(
                    af[fm], bf[fn], acc[fm][fn], 0, 0, 0);
    }

    const int orow = (lane >> 4) * 4;  // C/D: col = lane&15, row = (lane>>4)*4 + r
#pragma unroll
    for (int fm = 0; fm < 4; ++fm) {
#pragma unroll
        for (int fn = 0; fn < 4; ++fn) {
            const int n = n0 + wn + fn * 16 + fr;
            const float bn = bias[n];
#pragma unroll
            for (int r = 0; r < 4; ++r) {
                const int m = m0 + wm + fm * 16 + orow + r;
                float v = fmaxf(acc[fm][fn][r] + bn, 0.f);
                if (OUT_BF16)
                    ((__hip_bfloat16*)Cout)[(size_t)m * N + n] = __float2bfloat16(v);
                else
                    ((float*)Cout)[(size_t)m * N + n] = v;
            }
        }
    }
}

// ------------------------------------------------- FC3 + log_softmax (fp32)
__global__ __launch_bounds__(256) void fc3_logsoftmax(
    const float* __restrict__ A,  // (32768, 128) f32
    const float* __restrict__ W,  // (128, 5)
    const float* __restrict__ b,
    float* __restrict__ out,      // (32768, 5)
    int M)
{
    __shared__ float sW[128 * 5];
    __shared__ float sB[5];
    const int t = threadIdx.x;
    for (int i = t; i < 640; i += 256) sW[i] = W[i];
    if (t < 5) sB[t] = b[t];
    __syncthreads();

    int row = blockIdx.x * blockDim.x + t;
    if (row >= M) return;
    float logits[5];
#pragma unroll
    for (int j = 0; j < 5; ++j) logits[j] = sB[j];
    const float* a = A + (size_t)row * 128;
    for (int k = 0; k < 128; k += 4) {
        float4 av = *(const float4*)&a[k];
        const float* wk = sW + k * 5;
#pragma unroll
        for (int j = 0; j < 5; ++j) logits[j] = fmaf(av.x, wk[j], logits[j]);
#pragma unroll
        for (int j = 0; j < 5; ++j) logits[j] = fmaf(av.y, wk[5 + j], logits[j]);
#pragma unroll
        for (int j = 0; j < 5; ++j) logits[j] = fmaf(av.z, wk[10 + j], logits[j]);
#pragma unroll
        for (int j = 0; j < 5; ++j) logits[j] = fmaf(av.w, wk[15 + j], logits[j]);
    }
    float mx = logits[0];
#pragma unroll
    for (int j = 1; j < 5; ++j) mx = fmaxf(mx, logits[j]);
    float s = 0.f;
#pragma unroll
    for (int j = 0; j < 5; ++j) s += expf(logits[j] - mx);
    float lse = mx + logf(s);
#pragma unroll
    for (int j = 0; j < 5; ++j) out[(size_t)row * 5 + j] = logits[j] - lse;
}

extern "C" void kernel_launch(void* const* d_in, const int* in_sizes, int n_in,
                              void* d_out, int out_size, void* d_ws, size_t ws_size,
                              hipStream_t stream) {
    const float* x     = (const float*)d_in[0];
    // d_in[1], d_in[2]: edge_src/edge_dst — structure is static, unused
    const float* ew    = (const float*)d_in[3];
    const float* w1    = (const float*)d_in[4];
    const float* b1    = (const float*)d_in[5];
    const float* w2    = (const float*)d_in[6];
    const float* b2    = (const float*)d_in[7];
    const float* w3    = (const float*)d_in[8];
    const float* b3    = (const float*)d_in[9];
    const float* fc1_w = (const float*)d_in[10];
    const float* fc1_b = (const float*)d_in[11];
    const float* fc2_w = (const float*)d_in[12];
    const float* fc2_b = (const float*)d_in[13];
    const float* fc3_w = (const float*)d_in[14];
    const float* fc3_b = (const float*)d_in[15];
    float* out = (float*)d_out;

    // ws layout: h3 bf16 32MB | a1 bf16 16MB | a2 f32 16MB | Wt1 | Wt2
    char* p = (char*)d_ws;
    __hip_bfloat16* h3  = (__hip_bfloat16*)p;                 p += (size_t)NGRAPH * 512 * 2;
    __hip_bfloat16* a1  = (__hip_bfloat16*)p;                 p += (size_t)NGRAPH * 256 * 2;
    float*          a2  = (float*)p;                          p += (size_t)NGRAPH * 128 * 4;
    __hip_bfloat16* Wt1 = (__hip_bfloat16*)p;                 p += (size_t)256 * 512 * 2;
    __hip_bfloat16* Wt2 = (__hip_bfloat16*)p;

    transpose_cast<<<dim3(512 / 32, 256 / 32), 256, 0, stream>>>(fc1_w, Wt1, 512, 256);
    transpose_cast<<<dim3(256 / 32, 128 / 32), 256, 0, stream>>>(fc2_w, Wt2, 256, 128);
    cheb_fused<<<NGRAPH / 4, 256, 0, stream>>>(x, ew, w1, b1, w2, b2, w3, b3, h3);
    mfma_fc<true ><<<dim3(NGRAPH / 128, 256 / 128), 256, 0, stream>>>(h3, Wt1, fc1_b, a1,
                                                                      NGRAPH, 256, 512);
    mfma_fc<false><<<dim3(NGRAPH / 128, 128 / 128), 256, 0, stream>>>(a1, Wt2, fc2_b, a2,
                                                                      NGRAPH, 128, 256);
    fc3_logsoftmax<<<NGRAPH / 256, 256, 0, stream>>>(a2, fc3_w, fc3_b, out, NGRAPH);
}